// Round 7
// baseline (428.138 us; speedup 1.0000x reference)
//
#include <hip/hip_runtime.h>
#include <math.h>

// Problem constants (match reference)
#define B   64
#define C   256
#define CR  16
#define HW  3136          // 56*56
#define NV4 784           // HW/4 (784 = 3*256 + 16)

// ---------------------------------------------------------------------------
// Kernel 1: global average pool over H,W for each (b,c) plane.
// One block per plane; float4 vectorized loads; wave shuffle + LDS reduce.
// ---------------------------------------------------------------------------
__global__ __launch_bounds__(256) void se_pool(const float* __restrict__ in,
                                               float* __restrict__ pooled) {
    const int plane = blockIdx.x;  // b*C + c
    const float4* p = reinterpret_cast<const float4*>(in + (size_t)plane * HW);

    float s = 0.f;
    for (int i = threadIdx.x; i < NV4; i += 256) {
        float4 v = p[i];
        s += (v.x + v.y) + (v.z + v.w);
    }
    // intra-wave butterfly (wave = 64 lanes)
    #pragma unroll
    for (int off = 32; off > 0; off >>= 1)
        s += __shfl_down(s, off, 64);

    __shared__ float wsum[4];
    const int lane = threadIdx.x & 63;
    const int wid  = threadIdx.x >> 6;
    if (lane == 0) wsum[wid] = s;
    __syncthreads();
    if (threadIdx.x == 0) {
        float t = (wsum[0] + wsum[1]) + (wsum[2] + wsum[3]);
        pooled[plane] = t * (1.0f / (float)HW);
    }
}

// ---------------------------------------------------------------------------
// Kernel 2 (fused): per-plane gate compute + channel-wise rescale.
// One block per (b,c) plane. The block:
//   1. issues its plane's float4 loads into registers (HBM latency starts)
//   2. loads pooled[b,:] to LDS, computes h = relu(pooled@w1^T+b1) (16 thr),
//      then g = sigmoid(h . w2[c,:] + b2[c]) (1 thr) — hidden under (1)
//   3. multiplies the prefetched registers by g and stores.
// w1 (16 KB) / w2 row / b1 / b2 are L1/L2-resident across the 16384 blocks;
// the redundant ~4K FLOPs per block are free on a memory-bound kernel.
// ---------------------------------------------------------------------------
__global__ __launch_bounds__(256) void se_scale_fused(const float* __restrict__ in,
                                                      const float* __restrict__ pooled,
                                                      const float* __restrict__ w1,
                                                      const float* __restrict__ b1,
                                                      const float* __restrict__ w2,
                                                      const float* __restrict__ b2,
                                                      float* __restrict__ out) {
    const int plane = blockIdx.x;      // b*C + c
    const int b = plane >> 8;          // / C
    const int c = plane & (C - 1);     // % C
    const int t = threadIdx.x;

    const float4* pi = reinterpret_cast<const float4*>(in + (size_t)plane * HW);
    float4* po = reinterpret_cast<float4*>(out + (size_t)plane * HW);

    // --- 1. register prefetch of this plane (threads 0..15 hold 4, rest 3) ---
    float4 r0, r1, r2, r3;
    r0 = pi[t];
    r1 = pi[t + 256];
    r2 = pi[t + 512];
    const bool has4 = (t < NV4 - 768);   // t < 16
    if (has4) r3 = pi[t + 768];

    // --- 2. gate compute (overlaps with outstanding loads above) ---
    __shared__ float sp[C];
    __shared__ float sh[CR];
    __shared__ float sg;

    sp[t] = pooled[b * C + t];
    __syncthreads();

    if (t < CR) {
        float acc = b1[t];
        const float* wrow = w1 + t * C;   // w1 is [CR, C]
        #pragma unroll 8
        for (int k = 0; k < C; ++k) acc = fmaf(sp[k], wrow[k], acc);
        sh[t] = fmaxf(acc, 0.f);
    }
    __syncthreads();

    if (t == 0) {
        float acc = b2[c];
        const float* wrow = w2 + c * CR;  // w2 is [C, CR]
        #pragma unroll
        for (int k = 0; k < CR; ++k) acc = fmaf(sh[k], wrow[k], acc);
        sg = 1.0f / (1.0f + expf(-acc));
    }
    __syncthreads();
    const float g = sg;

    // --- 3. scale + store ---
    r0.x *= g; r0.y *= g; r0.z *= g; r0.w *= g;
    r1.x *= g; r1.y *= g; r1.z *= g; r1.w *= g;
    r2.x *= g; r2.y *= g; r2.z *= g; r2.w *= g;
    po[t]       = r0;
    po[t + 256] = r1;
    po[t + 512] = r2;
    if (has4) {
        r3.x *= g; r3.y *= g; r3.z *= g; r3.w *= g;
        po[t + 768] = r3;
    }
}

extern "C" void kernel_launch(void* const* d_in, const int* in_sizes, int n_in,
                              void* d_out, int out_size, void* d_ws, size_t ws_size,
                              hipStream_t stream) {
    const float* feat = (const float*)d_in[0];
    const float* w1   = (const float*)d_in[1];
    const float* b1   = (const float*)d_in[2];
    const float* w2   = (const float*)d_in[3];
    const float* b2   = (const float*)d_in[4];
    float* out = (float*)d_out;

    float* pooled = (float*)d_ws;   // B*C floats = 64 KiB scratch

    se_pool<<<B * C, 256, 0, stream>>>(feat, pooled);
    se_scale_fused<<<B * C, 256, 0, stream>>>(feat, pooled, w1, b1, w2, b2, out);
}

// Round 10
// 416.955 us; speedup vs baseline: 1.0268x; 1.0268x over previous
//
#include <hip/hip_runtime.h>
#include <math.h>

// Problem constants (match reference)
#define B   64
#define C   256
#define CR  16
#define HW  3136          // 56*56
#define NV4 784           // HW/4 (784 = 3*256 + 16)

typedef float vf4 __attribute__((ext_vector_type(4)));   // clang vector: valid
                                                         // for nontemporal builtins

// ---------------------------------------------------------------------------
// Kernel 1: global average pool over H,W for each (b,c) plane.
// One block per plane; float4 vectorized loads; wave shuffle + LDS reduce.
// Regular (caching) loads on purpose: this read warms L3 for kernel 2.
// ---------------------------------------------------------------------------
__global__ __launch_bounds__(256) void se_pool(const float* __restrict__ in,
                                               float* __restrict__ pooled) {
    const int plane = blockIdx.x;  // b*C + c
    const vf4* p = reinterpret_cast<const vf4*>(in + (size_t)plane * HW);

    float s = 0.f;
    for (int i = threadIdx.x; i < NV4; i += 256) {
        vf4 v = p[i];
        s += (v.x + v.y) + (v.z + v.w);
    }
    // intra-wave butterfly (wave = 64 lanes)
    #pragma unroll
    for (int off = 32; off > 0; off >>= 1)
        s += __shfl_down(s, off, 64);

    __shared__ float wsum[4];
    const int lane = threadIdx.x & 63;
    const int wid  = threadIdx.x >> 6;
    if (lane == 0) wsum[wid] = s;
    __syncthreads();
    if (threadIdx.x == 0) {
        float t = (wsum[0] + wsum[1]) + (wsum[2] + wsum[3]);
        pooled[plane] = t * (1.0f / (float)HW);
    }
}

// ---------------------------------------------------------------------------
// Kernel 2 (fused): per-plane gate compute + channel-wise rescale.
// One block per (b,c) plane:
//   1. register-prefetch the plane (HBM/L3 latency starts immediately)
//   2. gate = sigmoid(relu(pooled@w1^T+b1) . w2[c,:] + b2[c]) — hidden under 1
//   3. scale prefetched registers, store NON-TEMPORAL so the 205 MB output
//      write doesn't evict the L3-resident input that later blocks re-read.
// ---------------------------------------------------------------------------
__global__ __launch_bounds__(256) void se_scale_fused(const float* __restrict__ in,
                                                      const float* __restrict__ pooled,
                                                      const float* __restrict__ w1,
                                                      const float* __restrict__ b1,
                                                      const float* __restrict__ w2,
                                                      const float* __restrict__ b2,
                                                      float* __restrict__ out) {
    const int plane = blockIdx.x;      // b*C + c
    const int b = plane >> 8;          // / C
    const int c = plane & (C - 1);     // % C
    const int t = threadIdx.x;

    const vf4* pi = reinterpret_cast<const vf4*>(in + (size_t)plane * HW);
    vf4* po = reinterpret_cast<vf4*>(out + (size_t)plane * HW);

    // --- 1. register prefetch of this plane (threads 0..15 hold 4, rest 3) ---
    vf4 r0, r1, r2, r3;
    r0 = pi[t];
    r1 = pi[t + 256];
    r2 = pi[t + 512];
    const bool has4 = (t < NV4 - 768);   // t < 16
    if (has4) r3 = pi[t + 768];

    // --- 2. gate compute (overlaps with outstanding loads above) ---
    __shared__ float sp[C];
    __shared__ float sh[CR];
    __shared__ float sg;

    sp[t] = pooled[b * C + t];
    __syncthreads();

    if (t < CR) {
        float acc = b1[t];
        const float* wrow = w1 + t * C;   // w1 is [CR, C]
        #pragma unroll 8
        for (int k = 0; k < C; ++k) acc = fmaf(sp[k], wrow[k], acc);
        sh[t] = fmaxf(acc, 0.f);
    }
    __syncthreads();

    if (t == 0) {
        float acc = b2[c];
        const float* wrow = w2 + c * CR;  // w2 is [C, CR]
        #pragma unroll
        for (int k = 0; k < CR; ++k) acc = fmaf(sh[k], wrow[k], acc);
        sg = 1.0f / (1.0f + expf(-acc));
    }
    __syncthreads();
    const float g = sg;

    // --- 3. scale + non-temporal store ---
    r0 *= g;
    r1 *= g;
    r2 *= g;
    __builtin_nontemporal_store(r0, po + t);
    __builtin_nontemporal_store(r1, po + t + 256);
    __builtin_nontemporal_store(r2, po + t + 512);
    if (has4) {
        r3 *= g;
        __builtin_nontemporal_store(r3, po + t + 768);
    }
}

extern "C" void kernel_launch(void* const* d_in, const int* in_sizes, int n_in,
                              void* d_out, int out_size, void* d_ws, size_t ws_size,
                              hipStream_t stream) {
    const float* feat = (const float*)d_in[0];
    const float* w1   = (const float*)d_in[1];
    const float* b1   = (const float*)d_in[2];
    const float* w2   = (const float*)d_in[3];
    const float* b2   = (const float*)d_in[4];
    float* out = (float*)d_out;

    float* pooled = (float*)d_ws;   // B*C floats = 64 KiB scratch

    se_pool<<<B * C, 256, 0, stream>>>(feat, pooled);
    se_scale_fused<<<B * C, 256, 0, stream>>>(feat, pooled, w1, b1, w2, b2, out);
}